// Round 11
// baseline (34.310 us; speedup 1.0000x reference)
//
#include <hip/hip_runtime.h>
#include <math.h>

#define N_RAYS 16384
#define FEAT 15
#define BOUNDF 2.0f
#define MIN_NEAR 0.05f
#define PRW 1232           // per-ray LDS words (4928 B)
#define RPB 4              // rays per 128-thread block (2 waves x 2 rays)

// per-ray LDS word offsets — same aliasing discipline as R10 (proven):
//   stage 0..659 live per MLP pass; cdf 0..127 written after coarse readback,
//   consumed before fine pass rewrites stage; HU/HM 660..920 consumed before
//   sorted scatter writes 0..1023; zf/AB/bias 1024..1231 un-aliased.
#define O_STG  0
#define O_CDF  0
#define O_ZS   0
#define O_SIG  256
#define O_RGB  512
#define O_HU   660
#define O_HM   792
#define O_ZF   1024
#define O_AB   1152
#define O_BIAS 1216

typedef __fp16 h16x2 __attribute__((ext_vector_type(2)));
typedef _Float16 f16x8 __attribute__((ext_vector_type(8)));
typedef float f32x4 __attribute__((ext_vector_type(4)));
typedef float f32x2v __attribute__((ext_vector_type(2)));

#define WS_FRAG 0
#define WS_BF   256
#define WS_B20  260

__device__ __forceinline__ h16x2 pk_fma_f16(h16x2 a, h16x2 b, h16x2 c) {
    h16x2 d;
    asm("v_pk_fma_f16 %0, %1, %2, %3" : "=v"(d) : "v"(a), "v"(b), "v"(c));
    return d;
}
__device__ __forceinline__ h16x2 pk_relu_f16(h16x2 a) {
    h16x2 d;
    asm("v_pk_max_f16 %0, %1, 0" : "=v"(d) : "v"(a));
    return d;
}
__device__ __forceinline__ float softplus_f(float x) {
    float e = __builtin_amdgcn_exp2f(x * 1.442695041f);
    return 0.69314718056f * __builtin_amdgcn_logf(1.0f + e);
}
__device__ __forceinline__ float sigmoid_f(float x) {
    float e = __builtin_amdgcn_exp2f(x * -1.442695041f);
    return __builtin_amdgcn_rcpf(1.0f + e);
}
__device__ __forceinline__ float clampf(float x, float lo, float hi) {
    return fminf(fmaxf(x, lo), hi);
}
__device__ __forceinline__ uint2 pack_rgb(float c0, float c1, float c2, float c3) {
    h16x2 p0 = __builtin_amdgcn_cvt_pkrtz(c0, c1);
    h16x2 p1 = __builtin_amdgcn_cvt_pkrtz(c2, c3);
    uint2 r;
    r.x = __builtin_bit_cast(unsigned int, p0);
    r.y = __builtin_bit_cast(unsigned int, p1);
    return r;
}
__device__ __forceinline__ void unpack_rgb(unsigned int lo, unsigned int hi, float* c) {
    h16x2 p0 = __builtin_bit_cast(h16x2, lo);
    h16x2 p1 = __builtin_bit_cast(h16x2, hi);
    c[0] = (float)p0.x; c[1] = (float)p0.y; c[2] = (float)p1.x; c[3] = (float)p1.y;
}

// ---- DPP 32-lane SEGMENTED inclusive scans (5 steps, no bcast31) ----
template<int CTRL, int RMASK>
__device__ __forceinline__ float dppf(float old, float v) {
    int r = __builtin_amdgcn_update_dpp(__builtin_bit_cast(int, old),
                                        __builtin_bit_cast(int, v),
                                        CTRL, RMASK, 0xf, false);
    return __builtin_bit_cast(float, r);
}
template<int CTRL, int RMASK>
__device__ __forceinline__ int dppi(int old, int v) {
    return __builtin_amdgcn_update_dpp(old, v, CTRL, RMASK, 0xf, false);
}
__device__ __forceinline__ float seg_scan_mul(float v) {
    v *= dppf<0x111, 0xf>(1.0f, v);   // row_shr:1
    v *= dppf<0x112, 0xf>(1.0f, v);   // row_shr:2
    v *= dppf<0x114, 0xf>(1.0f, v);   // row_shr:4
    v *= dppf<0x118, 0xf>(1.0f, v);   // row_shr:8
    v *= dppf<0x142, 0xa>(1.0f, v);   // row_bcast:15 -> rows 1,3 (stays in 32-seg)
    return v;
}
__device__ __forceinline__ float seg_scan_add(float v) {
    v += dppf<0x111, 0xf>(0.0f, v);
    v += dppf<0x112, 0xf>(0.0f, v);
    v += dppf<0x114, 0xf>(0.0f, v);
    v += dppf<0x118, 0xf>(0.0f, v);
    v += dppf<0x142, 0xa>(0.0f, v);
    return v;
}
__device__ __forceinline__ int seg_scan_add_i(int v) {
    v += dppi<0x111, 0xf>(0, v);
    v += dppi<0x112, 0xf>(0, v);
    v += dppi<0x114, 0xf>(0, v);
    v += dppi<0x118, 0xf>(0, v);
    v += dppi<0x142, 0xa>(0, v);
    return v;
}

// B-fragment prep (unchanged from R9/R10, proven)
extern "C" __global__ __launch_bounds__(64)
void nerf_prep_kernel(const float* __restrict__ W2, const float* __restrict__ b2,
                      const float* __restrict__ Wc, const float* __restrict__ bc,
                      float* __restrict__ ws) {
    const int t = threadIdx.x;
    const int col = t & 15, kb = t >> 4;
    float v[8];
#pragma unroll
    for (int j = 0; j < 8; ++j) {
        const int k = kb * 8 + j;
        float x = 0.0f;
        if (col == 0) {
            x = W2[k * 16];
        } else if (col <= 4) {
#pragma unroll
            for (int f = 0; f < FEAT; ++f) x += W2[k * 16 + 1 + f] * Wc[f * 4 + (col - 1)];
        }
        v[j] = x;
    }
#pragma unroll
    for (int m = 0; m < 4; ++m) {
        h16x2 p = __builtin_amdgcn_cvt_pkrtz(v[2 * m], v[2 * m + 1]);
        ws[WS_FRAG + t * 4 + m] = __builtin_bit_cast(float, p);
    }
    if (t < 4) {
        float b = bc[t];
#pragma unroll
        for (int f = 0; f < FEAT; ++f) b += b2[1 + f] * Wc[f * 4 + t];
        ws[WS_BF + t] = b;
    }
    if (t == 0) ws[WS_B20] = b2[0];
}

extern "C" __global__ __launch_bounds__(128, 4)
void nerf_render_kernel(const float* __restrict__ rays_o,
                        const float* __restrict__ rays_d,
                        const float* __restrict__ W1, const float* __restrict__ b1,
                        const float* __restrict__ Wd,
                        const float* __restrict__ wsf,
                        float* __restrict__ out) {
    const int wv    = threadIdx.x >> 6;
    const int lane  = threadIdx.x & 63;
    const int seg   = lane >> 5;          // ray within wave
    const int sl    = lane & 31;          // lane within 32-seg
    const int col16 = lane & 15;
    const int kb    = lane >> 4;
    const int ray   = blockIdx.x * RPB + wv * 2 + seg;

    __shared__ __align__(16) float smem[RPB][PRW];
    float* baseO = &smem[wv * 2 + seg][0];   // own ray region
    float* base0 = &smem[wv * 2 + 0][0];
    float* base1 = &smem[wv * 2 + 1][0];
    int*   sHUo  = (int*)(baseO + O_HU);
    int*   sHMo  = (int*)(baseO + O_HM);

    // ---- per-ray setup (each segment handles its own ray) ----
    const float ox = rays_o[ray * 3 + 0], oy = rays_o[ray * 3 + 1], oz = rays_o[ray * 3 + 2];
    const float dx = rays_d[ray * 3 + 0], dy = rays_d[ray * 3 + 1], dz = rays_d[ray * 3 + 2];

    auto invd = [](float d) { float dd = (fabsf(d) < 1e-9f) ? 1e-9f : d; return 1.0f / dd; };
    const float ixv = invd(dx), iyv = invd(dy), izv = invd(dz);
    const float t1x = (-BOUNDF - ox) * ixv, t2x = (BOUNDF - ox) * ixv;
    const float t1y = (-BOUNDF - oy) * iyv, t2y = (BOUNDF - oy) * iyv;
    const float t1z = (-BOUNDF - oz) * izv, t2z = (BOUNDF - oz) * izv;
    float nearv = fmaxf(fmaxf(fminf(t1x, t2x), fminf(t1y, t2y)), fminf(t1z, t2z));
    nearv = fmaxf(nearv, MIN_NEAR);
    float farv = fminf(fminf(fmaxf(t1x, t2x), fmaxf(t1y, t2y)), fmaxf(t1z, t2z));
    farv = fmaxf(farv, nearv + 1e-5f);
    const float fmn = farv - nearv;
    const float sample_dist = fmn * (1.0f / 128.0f);
    const float dstep = fmn * (1.0f / 127.0f);

    // zero own histograms (int4 stores; entries 0..127 + [128])
    {
        int4 z4i; z4i.x = 0; z4i.y = 0; z4i.z = 0; z4i.w = 0;
        *(int4*)(sHUo + 4 * sl) = z4i;
        *(int4*)(sHMo + 4 * sl) = z4i;
        if (sl == 0) { sHUo[128] = 0; sHMo[128] = 0; }
    }

    // layer-1 fold into own region: every lane writes j = sl for its ray
    {
        const int j = sl;
        const float w0 = W1[j], w1 = W1[32 + j], w2 = W1[64 + j];
        float* sABo = baseO + O_AB;
        sABo[(j >> 1) * 4 + (j & 1)]     = b1[j] + ox * w0 + oy * w1 + oz * w2;
        sABo[(j >> 1) * 4 + 2 + (j & 1)] = dx * w0 + dy * w1 + dz * w2;
    }
    // acc-init bias per output col (16 per ray; sl<16 of each segment)
    if (sl < 16) {
        float b = 0.0f;
        if (sl == 0) b = wsf[WS_B20];
        else if (sl <= 4) {
            const int c = sl - 1;
            b = wsf[WS_BF + c] + dx * Wd[c] + dy * Wd[4 + c] + dz * Wd[8 + c];
        }
        (baseO + O_BIAS)[sl] = b;
    }
    __builtin_amdgcn_wave_barrier();

    // broadcast both rays' grid params to all lanes
    const float nv0 = __shfl(nearv, 0, 64),  nv1 = __shfl(nearv, 32, 64);
    const float dt0 = __shfl(dstep, 0, 64),  dt1 = __shfl(dstep, 32, 64);

    // per-lane fragments for BOTH rays
    h16x2 Af0[4], Bf0[4], Af1[4], Bf1[4];
#pragma unroll
    for (int m = 0; m < 4; ++m) {
        const float4 a0 = ((const float4*)(base0 + O_AB))[kb * 4 + m];
        Af0[m] = __builtin_amdgcn_cvt_pkrtz(a0.x, a0.y);
        Bf0[m] = __builtin_amdgcn_cvt_pkrtz(a0.z, a0.w);
        const float4 a1 = ((const float4*)(base1 + O_AB))[kb * 4 + m];
        Af1[m] = __builtin_amdgcn_cvt_pkrtz(a1.x, a1.y);
        Bf1[m] = __builtin_amdgcn_cvt_pkrtz(a1.z, a1.w);
    }
    const float4 frw = ((const float4*)wsf)[lane];
    const f16x8 bfrag = __builtin_bit_cast(f16x8, frw);
    const float bv0 = (base0 + O_BIAS)[col16];
    const float bv1 = (base1 + O_BIAS)[col16];
    f32x4 acc0; acc0[0] = bv0; acc0[1] = bv0; acc0[2] = bv0; acc0[3] = bv0;
    f32x4 acc1; acc1[0] = bv1; acc1[1] = bv1; acc1[2] = bv1; acc1[3] = bv1;

    // ---- MFMA MLP pass for one ray: 8 tiles of 16 samples ----
    auto mlp_pass = [&](float* stg, const float* zsrc, float nv, float dt,
                        const h16x2* Af, const h16x2* Bf, const f32x4& accB) {
#pragma unroll
        for (int tt = 0; tt < 8; ++tt) {
            float zs;
            if (zsrc) zs = zsrc[tt * 16 + col16];
            else      zs = fmaf((float)(tt * 16 + col16), dt, nv);
            const h16x2 z2 = __builtin_amdgcn_cvt_pkrtz(zs, zs);
            h16x2 h0 = pk_relu_f16(pk_fma_f16(Bf[0], z2, Af[0]));
            h16x2 h1 = pk_relu_f16(pk_fma_f16(Bf[1], z2, Af[1]));
            h16x2 h2 = pk_relu_f16(pk_fma_f16(Bf[2], z2, Af[2]));
            h16x2 h3 = pk_relu_f16(pk_fma_f16(Bf[3], z2, Af[3]));
            uint4 au;
            au.x = __builtin_bit_cast(unsigned int, h0);
            au.y = __builtin_bit_cast(unsigned int, h1);
            au.z = __builtin_bit_cast(unsigned int, h2);
            au.w = __builtin_bit_cast(unsigned int, h3);
            const f16x8 afrag = __builtin_bit_cast(f16x8, au);
            f32x4 acc = __builtin_amdgcn_mfma_f32_16x16x32_f16(afrag, bfrag, accB, 0, 0, 0);
            if (col16 < 5)
                *(f32x4*)&stg[col16 * 132 + tt * 16 + kb * 4] = acc;
        }
    };
    // own-ray readback: 4 samples (4sl..4sl+3) via 5 x b128
    auto readback = [&](float* sg, uint2* rgb) {
        const f32x4 c0 = *(const f32x4*)&baseO[O_STG + 0 * 132 + 4 * sl];
        const f32x4 c1 = *(const f32x4*)&baseO[O_STG + 1 * 132 + 4 * sl];
        const f32x4 c2 = *(const f32x4*)&baseO[O_STG + 2 * 132 + 4 * sl];
        const f32x4 c3 = *(const f32x4*)&baseO[O_STG + 3 * 132 + 4 * sl];
        const f32x4 c4 = *(const f32x4*)&baseO[O_STG + 4 * 132 + 4 * sl];
#pragma unroll
        for (int i = 0; i < 4; ++i) {
            sg[i]  = softplus_f(c0[i]);
            rgb[i] = pack_rgb(sigmoid_f(c1[i]), sigmoid_f(c2[i]),
                              sigmoid_f(c3[i]), sigmoid_f(c4[i]));
        }
    };

    // ---- coarse pass (both rays) ----
    mlp_pass(base0 + O_STG, nullptr, nv0, dt0, Af0, Bf0, acc0);
    mlp_pass(base1 + O_STG, nullptr, nv1, dt1, Af1, Bf1, acc1);
    __builtin_amdgcn_wave_barrier();
    float sgc[4]; uint2 rgc[4];
    readback(sgc, rgc);
    __builtin_amdgcn_wave_barrier();    // stage consumed; cdf may overwrite

    // ---- coarse composite weights (per own ray; 4 samples/lane) ----
    float alc[4], vvc[4];
#pragma unroll
    for (int c = 0; c < 4; ++c) {
        float del = (sl == 31 && c == 3) ? sample_dist : dstep;
        const float e = __builtin_amdgcn_exp2f(del * sgc[c] * -1.442695041f);
        alc[c] = 1.0f - e;
        vvc[c] = e + 1e-15f;
    }
    const float incl = seg_scan_mul(vvc[0] * vvc[1] * vvc[2] * vvc[3]);
    float excl = __shfl_up(incl, 1, 64);
    if (sl == 0) excl = 1.0f;
    const float w0c = alc[0] * excl;
    const float w1c = alc[1] * excl * vvc[0];
    const float w2c = alc[2] * excl * vvc[0] * vvc[1];
    const float w3c = alc[3] * excl * vvc[0] * vvc[1] * vvc[2];

    // pdf bins j=0..125: lane sl handles bins 4sl..4sl+3, pdf_j = w[j+1]+1e-5
    const float wnext = __shfl_down(w0c, 1, 64);
    float p0 = w1c + 1e-5f, p1 = w2c + 1e-5f, p2 = w3c + 1e-5f, p3 = wnext + 1e-5f;
    if (sl == 31) { p2 = 0.0f; p3 = 0.0f; }
    const float psum = p0 + p1 + p2 + p3;
    const float cinc = seg_scan_add(psum);
    const float total = __shfl(cinc, (lane & 32) | 31, 64);
    const float rtot = __builtin_amdgcn_rcpf(total);
    const float cexcl = cinc - psum;
    {
        float cs = cexcl;
        const float pv[4] = {p0, p1, p2, p3};
#pragma unroll
        for (int c = 0; c < 4; ++c) {
            cs += pv[c];
            const int idx = 4 * sl + 1 + c;
            if (idx <= 126) {
                const float val = cs * rtot;
                baseO[O_CDF + idx] = val;
                int cnt = (int)ceilf(fmaf(128.0f, val, -0.5f));
                cnt = min(max(cnt, 0), 128);
                atomicAdd(&sHUo[cnt], 1);
            }
        }
        if (sl == 31) {
            baseO[O_CDF + 0] = 0.0f;
            atomicAdd(&sHUo[0], 1);
        }
    }
    __builtin_amdgcn_wave_barrier();

    // ---- inds via segmented histogram prefix; 4 lerps; ranks ----
    const int4 hu = *(const int4*)(sHUo + 4 * sl);
    const int hs = hu.x + hu.y + hu.z + hu.w;
    const int hscan = seg_scan_add_i(hs);
    const int hexcl = hscan - hs;
    int inds[4];
    inds[0] = hexcl + hu.x;
    inds[1] = inds[0] + hu.y;
    inds[2] = inds[1] + hu.z;
    inds[3] = inds[2] + hu.w;

    auto lerp_z = [&](int ii, float u) -> float {
        const int below = ii - 1;
        const int above = min(ii, 126);
        const float cb = baseO[O_CDF + below], ca = baseO[O_CDF + above];
        const float bb = fmaf((float)below + 0.5f, dstep, nearv);
        const float ba = fmaf((float)above + 0.5f, dstep, nearv);
        float den = ca - cb;
        if (den < 1e-5f) den = 1.0f;
        const float t = (u - cb) * __builtin_amdgcn_rcpf(den);
        return bb + t * (ba - bb);
    };
    float zff[4]; int rr[4];
    const float inv_stepz = 127.0f / fmn;
#pragma unroll
    for (int c = 0; c < 4; ++c) {
        const float u = ((float)(4 * sl + c) + 0.5f) * (1.0f / 128.0f);
        zff[c] = lerp_z(inds[c], u);
        int r = (int)floorf((zff[c] - nearv) * inv_stepz) + 1;
        rr[c] = min(max(r, 0), 128);
        atomicAdd(&sHMo[rr[c]], 1);
    }
    {
        f32x4 zfv; zfv[0] = zff[0]; zfv[1] = zff[1]; zfv[2] = zff[2]; zfv[3] = zff[3];
        *(f32x4*)&baseO[O_ZF + 4 * sl] = zfv;
    }
    __builtin_amdgcn_wave_barrier();    // cdf consumed; fine stage may overwrite

    // ---- fine pass (both rays) ----
    mlp_pass(base0 + O_STG, base0 + O_ZF, nv0, dt0, Af0, Bf0, acc0);
    mlp_pass(base1 + O_STG, base1 + O_ZF, nv1, dt1, Af1, Bf1, acc1);
    __builtin_amdgcn_wave_barrier();
    float sgf[4]; uint2 rgf[4];
    readback(sgf, rgf);
    __builtin_amdgcn_wave_barrier();    // stage consumed before sorted writes

    // ---- merge via segmented HM prefix; scatter 8 sorted triples ----
    const int4 hm = *(const int4*)(sHMo + 4 * sl);
    const int ms = hm.x + hm.y + hm.z + hm.w;
    const int mscan = seg_scan_add_i(ms);
    const int mexcl = mscan - ms;
    int gpre[4];
    gpre[0] = mexcl + hm.x;
    gpre[1] = gpre[0] + hm.y;
    gpre[2] = gpre[1] + hm.z;
    gpre[3] = gpre[2] + hm.w;

    auto il = [](int d) { return ((d & 3) << 6) + (d >> 2); };
    uint2* sRgbO = (uint2*)(baseO + O_RGB);
#pragma unroll
    for (int c = 0; c < 4; ++c) {
        const int idx = 4 * sl + c;
        const float zc = fmaf((float)idx, dstep, nearv);
        const int aC = il(idx + gpre[c]);
        baseO[O_ZS + aC] = zc;  baseO[O_SIG + aC] = sgc[c];  sRgbO[aC] = rgc[c];
        const int aF = il(idx + rr[c]);
        baseO[O_ZS + aF] = zff[c]; baseO[O_SIG + aF] = sgf[c]; sRgbO[aF] = rgf[c];
    }
    __builtin_amdgcn_wave_barrier();

    // ---- final compositing: 8 sorted samples per lane ----
    float z_[8], g_[8]; uint2 q_[8];
#pragma unroll
    for (int row = 0; row < 4; ++row) {
        const f32x2v zz = *(const f32x2v*)&baseO[O_ZS + row * 64 + 2 * sl];
        const f32x2v gg = *(const f32x2v*)&baseO[O_SIG + row * 64 + 2 * sl];
        const uint4  qq = *(const uint4*)(sRgbO + row * 64 + 2 * sl);
        z_[row] = zz[0]; z_[row + 4] = zz[1];
        g_[row] = gg[0]; g_[row + 4] = gg[1];
        q_[row].x = qq.x; q_[row].y = qq.y;
        q_[row + 4].x = qq.z; q_[row + 4].y = qq.w;
    }

    float dd[8];
#pragma unroll
    for (int c = 0; c < 7; ++c) dd[c] = z_[c + 1] - z_[c];
    const float znext = __shfl_down(z_[0], 1, 64);
    dd[7] = (sl == 31) ? sample_dist : (znext - z_[7]);

    float al[8], v[8];
#pragma unroll
    for (int c = 0; c < 8; ++c) {
        const float e = __builtin_amdgcn_exp2f(dd[c] * g_[c] * -1.442695041f);
        al[c] = 1.0f - e;
        v[c] = e + 1e-15f;
    }
    float prod = v[0];
#pragma unroll
    for (int c = 1; c < 8; ++c) prod *= v[c];
    const float incl2 = seg_scan_mul(prod);
    float T = __shfl_up(incl2, 1, 64);
    if (sl == 0) T = 1.0f;

    const float inv_fn = 1.0f / fmn;
    float vals[6] = {0.f, 0.f, 0.f, 0.f, 0.f, 0.f};
#pragma unroll
    for (int c = 0; c < 8; ++c) {
        const float w = al[c] * T;
        float rc[4];
        unpack_rgb(q_[c].x, q_[c].y, rc);
        vals[0] += w * rc[0]; vals[1] += w * rc[1];
        vals[2] += w * rc[2]; vals[3] += w * rc[3];
        const float ozv = clampf((z_[c] - nearv) * inv_fn, 0.0f, 1.0f);
        vals[4] += w * ozv;
        vals[5] += w;
        T *= v[c];
    }
#pragma unroll
    for (int q = 0; q < 6; ++q) vals[q] = seg_scan_add(vals[q]);

    if (sl == 31) {
        const float wsum = vals[5];
#pragma unroll
        for (int c = 0; c < 4; ++c)
            out[ray * 4 + c] = vals[c] + (1.0f - wsum);
        out[4 * N_RAYS + ray] = vals[4];
        out[5 * N_RAYS + ray] = wsum;
    }
}

extern "C" void kernel_launch(void* const* d_in, const int* in_sizes, int n_in,
                              void* d_out, int out_size, void* d_ws, size_t ws_size,
                              hipStream_t stream) {
    const float* rays_o = (const float*)d_in[0];
    const float* rays_d = (const float*)d_in[1];
    const float* W1 = (const float*)d_in[2];
    const float* b1 = (const float*)d_in[3];
    const float* W2 = (const float*)d_in[4];
    const float* b2 = (const float*)d_in[5];
    const float* Wc = (const float*)d_in[6];
    const float* Wd = (const float*)d_in[7];
    const float* bc = (const float*)d_in[8];
    float* out = (float*)d_out;
    float* ws  = (float*)d_ws;

    hipLaunchKernelGGL(nerf_prep_kernel, dim3(1), dim3(64), 0, stream,
                       W2, b2, Wc, bc, ws);
    hipLaunchKernelGGL(nerf_render_kernel, dim3(N_RAYS / RPB), dim3(128), 0, stream,
                       rays_o, rays_d, W1, b1, Wd, ws, out);
}